// Round 12
// baseline (231.610 us; speedup 1.0000x reference)
//
#include <hip/hip_runtime.h>
#include <math.h>

#define DDIM 1024
#define HDIM 128

typedef float  f32x4  __attribute__((ext_vector_type(4)));
typedef __bf16 bf16x8 __attribute__((ext_vector_type(8)));

union BF2U { __bf16 h; ushort u; };

__constant__ int c_perms[6][3] = {{0,1,2},{0,2,1},{1,0,2},{1,2,0},{2,0,1},{2,1,0}};

__device__ __forceinline__ ushort f2bf(float f){
    BF2U c; c.h = (__bf16)f; return c.u;
}
// branch-free gelu: Abramowitz-Stegun 7.1.26 erf (|err| < 1.5e-7), HW exp
__device__ __forceinline__ float gelu_fast(float x){
    float a = fabsf(x) * 0.70710678118654752f;
    float t = __frcp_rn(fmaf(0.3275911f, a, 1.0f));
    float p = t * fmaf(t, fmaf(t, fmaf(t, fmaf(t, 1.061405429f, -1.453152027f),
                 1.421413741f), -0.284496736f), 0.254829592f);
    float y = 1.0f - p * __expf(-a * a);
    float er = copysignf(y, x);
    return 0.5f * x * (1.0f + er);
}

// ---------------- K0: weight images (unchanged) ----------------
// w1s: 32 chunks t; halfword i = t*4096 + n*32 + kk = bf16(W1[t*32+kk][n])
// w2t: [n][k] bf16 swizzled: byte(n,k) = n*256 + ((k*2) ^ ((n&7)<<4))
__global__ __launch_bounds__(256) void k0_prep(const float* __restrict__ W1,
                                               const float* __restrict__ W2,
                                               ushort* __restrict__ w1s,
                                               ushort* __restrict__ w2t)
{
    int i = blockIdx.x * 256 + threadIdx.x;
    if (i < DDIM * HDIM) {
        int t = i >> 12, rem = i & 4095;
        int n = rem >> 5, kk = rem & 31;
        int k = t * 32 + kk;
        w1s[i] = f2bf(W1[(size_t)k * HDIM + n]);
    } else if (i < DDIM * HDIM + HDIM * HDIM) {
        int j = i - DDIM * HDIM;
        int k = j >> 7, n = j & 127;
        ushort b = f2bf(W2[(size_t)k * HDIM + n]);
        size_t off = (size_t)n * 256 + (size_t)(((k * 2) ^ ((n & 7) << 4)));
        w2t[off >> 1] = b;
    }
}

// ---------------- KF: fully wave-synchronous fused kernel ----------------
// 256 thr / 4 waves; wave w owns rows [blk*128 + w*32, +32) end-to-end:
// GEMM (A: private 3x4KB LDS ring, XOR-swizzled; B: 3-deep VGPR ring from L2)
// then recurrence on its own rows. Barriers ONLY at W2s staging + final reduce.
// LDS: W2s @0 (32KB) + per-wave arena @32768 + wid*12288 (12KB):
//   GEMM: A-ring bufs 0..2 at arena+{0,4096,8192}
//   phase B (aliased): Ct 8KB @arena+0, stl @arena+8192, loss @arena+8448
__global__ __launch_bounds__(256, 2) void kf_fused(
    const float* __restrict__ seq,
    const ushort* __restrict__ w1s,
    const ushort* __restrict__ w2t,
    const float* __restrict__ freq,
    const float* __restrict__ pres,
    const float* __restrict__ rmask,
    const int*   __restrict__ pidx,
    const float* __restrict__ W1,
    const float* __restrict__ b1,
    const float* __restrict__ b2,
    const float* __restrict__ W3,
    const float* __restrict__ b3,
    float* __restrict__ dec_f,
    float* __restrict__ dec_p,
    float* __restrict__ partials)
{
    __shared__ __align__(16) char lds[81920];
    const int t = threadIdx.x;
    const int wid = t >> 6, lane = t & 63;
    const int g = lane >> 4, ln = lane & 15;
    const size_t gr0 = (size_t)blockIdx.x * 128 + wid * 32;   // wave's first row

    // ---- stage W2s (32KB shared, identity copy of pre-swizzled w2t) ----
#pragma unroll
    for (int i = 0; i < 8; ++i) {
        const char* gs = (const char*)w2t + wid * 1024 + i * 4096 + lane * 16;
        char* ds = lds + wid * 1024 + i * 4096;
        __builtin_amdgcn_global_load_lds((const __attribute__((address_space(1))) void*)gs,
                                         (__attribute__((address_space(3))) void*)ds, 16, 0, 0);
    }
    asm volatile("s_waitcnt vmcnt(0)" ::: "memory");
    __syncthreads();                       // only barrier before the end

    char* const arena = lds + 32768 + wid * 12288;
    const int srow  = lane >> 3;                              // row-in-octet
    const int scolb = ((lane & 7) * 16) ^ ((lane >> 3) << 4); // XOR'd source byte
    const int boff  = ln * 64 + g * 16;                       // B-frag lane offset

#define STAGEA(BUF, TT) do { \
    _Pragma("unroll") \
    for (int j_ = 0; j_ < 4; ++j_) { \
        const char* ga_ = (const char*)(seq + (gr0 + j_ * 8 + srow) * DDIM) + (TT) * 128 + scolb; \
        char* la_ = arena + (BUF) * 4096 + j_ * 1024; \
        __builtin_amdgcn_global_load_lds((const __attribute__((address_space(1))) void*)ga_, \
                                         (__attribute__((address_space(3))) void*)la_, 16, 0, 0); \
    } } while (0)

#define LOADB(ARR, TT) do { \
    const char* bp_ = (const char*)w1s + (size_t)(TT) * 8192 + boff; \
    _Pragma("unroll") \
    for (int nf_ = 0; nf_ < 8; ++nf_) \
        ARR[nf_] = *reinterpret_cast<const bf16x8*>(bp_ + nf_ * 1024); \
    } while (0)

#define COMPUTE(BUF, ARR) do { \
    bf16x8 af[2]; \
    const int sw_ = (ln & 7) << 4; \
    _Pragma("unroll") \
    for (int mf_ = 0; mf_ < 2; ++mf_) { \
        const int p_ = mf_ * 16 + ln; \
        f32x4 x0 = *reinterpret_cast<const f32x4*>(arena + (BUF) * 4096 + p_ * 128 + ((g * 32 +  0) ^ sw_)); \
        f32x4 x1 = *reinterpret_cast<const f32x4*>(arena + (BUF) * 4096 + p_ * 128 + ((g * 32 + 16) ^ sw_)); \
        af[mf_][0] = (__bf16)x0[0]; af[mf_][1] = (__bf16)x0[1]; \
        af[mf_][2] = (__bf16)x0[2]; af[mf_][3] = (__bf16)x0[3]; \
        af[mf_][4] = (__bf16)x1[0]; af[mf_][5] = (__bf16)x1[1]; \
        af[mf_][6] = (__bf16)x1[2]; af[mf_][7] = (__bf16)x1[3]; \
    } \
    _Pragma("unroll") \
    for (int nf_ = 0; nf_ < 8; ++nf_) { \
        acc[0][nf_] = __builtin_amdgcn_mfma_f32_16x16x32_bf16(af[0], ARR[nf_], acc[0][nf_], 0, 0, 0); \
        acc[1][nf_] = __builtin_amdgcn_mfma_f32_16x16x32_bf16(af[1], ARR[nf_], acc[1][nf_], 0, 0, 0); \
    } } while (0)

#define WAITV(N) do { \
    asm volatile("s_waitcnt vmcnt(" #N ")" ::: "memory"); \
    __builtin_amdgcn_sched_barrier(0); } while (0)

    f32x4 acc[2][8];
#pragma unroll
    for (int m = 0; m < 2; ++m)
#pragma unroll
        for (int n = 0; n < 8; ++n) acc[m][n] = (f32x4){0.f, 0.f, 0.f, 0.f};

    bf16x8 bA[8], bB[8], bC[8];
    // prologue: 2 tiles in flight (12 loads each: 8 B + 4 A)
    LOADB(bA, 0); STAGEA(0, 0);
    LOADB(bB, 1); STAGEA(1, 1);

    for (int tt = 0; tt < 30; tt += 3) {
        WAITV(12); LOADB(bC, tt + 2); STAGEA(2, tt + 2); COMPUTE(0, bA);
        WAITV(12); LOADB(bA, tt + 3); STAGEA(0, tt + 3); COMPUTE(1, bB);
        WAITV(12); LOADB(bB, tt + 4); STAGEA(1, tt + 4); COMPUTE(2, bC);
    }
    WAITV(12); COMPUTE(0, bA);         // tile 30
    WAITV(0);  COMPUTE(1, bB);         // tile 31

#undef WAITV
#undef COMPUTE
#undef LOADB
#undef STAGEA

    // ---- epilogue: acc -> wave-private swizzled Ct (aliases A-ring; same-wave DS order)
    {
        float b1v[8];
#pragma unroll
        for (int nf = 0; nf < 8; ++nf) b1v[nf] = b1[nf * 16 + ln];
#pragma unroll
        for (int mf = 0; mf < 2; ++mf)
#pragma unroll
            for (int nf = 0; nf < 8; ++nf)
#pragma unroll
                for (int r = 0; r < 4; ++r) {
                    int p = mf * 16 + g * 4 + r;              // C/D map [m89]
                    int colb = (nf * 32 + ln * 2) ^ ((p & 7) << 4);
                    *reinterpret_cast<ushort*>(arena + p * 256 + colb) = f2bf(acc[mf][nf][r] + b1v[nf]);
                }
    }

    // ======== phase B: recurrence on own 32 rows (2 passes x 16), no barriers ========
    const char* W2s = lds;
    float* stl   = (float*)(arena + 8192);    // [16][2]
    float* lossw = (float*)(arena + 8448);

    float b2v[8], w30[8], w31[8];
#pragma unroll
    for (int nf = 0; nf < 8; ++nf) {
        b2v[nf] = b2[nf * 16 + ln];
        w30[nf] = W3[(nf * 16 + ln) * 2 + 0];
        w31[nf] = W3[(nf * 16 + ln) * 2 + 1];
    }
    const float b30 = b3[0], b31 = b3[1];
    const bool owner = (ln < 4);
    float lossAcc = 0.f, maskAcc = 0.f;

    for (int q = 0; q < 2; ++q) {
        const int prow = q * 16 + ln;          // own-panel Ct row for this lane's h1
        const size_t R_h = gr0 + prow;
        const int pidx_h = pidx[R_h];

        float scon[32];
        {
            const int swzr = (ln & 7) << 4;    // (prow&7) = ln&7
#pragma unroll
            for (int ks = 0; ks < 4; ++ks) {
                bf16x8 v = *reinterpret_cast<const bf16x8*>(arena + prow * 256 + ((ks * 64 + g * 16) ^ swzr));
#pragma unroll
                for (int j = 0; j < 8; ++j) scon[ks * 8 + j] = (float)v[j];
            }
        }
        const int rloc = g * 4 + ln;           // owner's row (ln<4)
        const size_t R_own = gr0 + q * 16 + rloc;
        int pio = 0;
        float ffo[3] = {0,0,0}, ppo[3] = {0,0,0}, mmo[3] = {0,0,0};
        if (owner) {
            pio = pidx[R_own];
#pragma unroll
            for (int qq = 0; qq < 3; ++qq) {
                ffo[qq] = freq[R_own * 3 + qq];
                ppo[qq] = pres[R_own * 3 + qq];
                mmo[qq] = rmask[R_own * 3 + qq];
            }
        }

        for (int s = 0; s < 3; ++s) {
            const int ridx_h = c_perms[pidx_h][s];
            bf16x8 afr[4];
#pragma unroll
            for (int ks = 0; ks < 4; ++ks) {
                const float* ohp = &W1[(size_t)(DDIM + 9 + ridx_h) * HDIM + ks * 32 + g * 8];
                f32x4 o0 = *reinterpret_cast<const f32x4*>(ohp);
                f32x4 o1 = *reinterpret_cast<const f32x4*>(ohp + 4);
#pragma unroll
                for (int j = 0; j < 4; ++j) {
                    afr[ks][j]     = (__bf16)gelu_fast(scon[ks * 8 + j]     + o0[j]);
                    afr[ks][4 + j] = (__bf16)gelu_fast(scon[ks * 8 + 4 + j] + o1[j]);
                }
            }
            f32x4 acc2[8];
#pragma unroll
            for (int nf = 0; nf < 8; ++nf) acc2[nf] = (f32x4){0.f, 0.f, 0.f, 0.f};
#pragma unroll
            for (int ks = 0; ks < 4; ++ks) {
#pragma unroll
                for (int nf = 0; nf < 8; ++nf) {
                    const int n = nf * 16 + ln;
                    bf16x8 bb = *reinterpret_cast<const bf16x8*>(W2s + n * 256 + ((ks * 64 + g * 16) ^ ((n & 7) << 4)));
                    acc2[nf] = __builtin_amdgcn_mfma_f32_16x16x32_bf16(afr[ks], bb, acc2[nf], 0, 0, 0);
                }
            }
            float p0[4] = {0, 0, 0, 0}, p1[4] = {0, 0, 0, 0};
#pragma unroll
            for (int nf = 0; nf < 8; ++nf) {
#pragma unroll
                for (int r = 0; r < 4; ++r) {
                    float h2 = gelu_fast(acc2[nf][r] + b2v[nf]);
                    p0[r] += h2 * w30[nf];
                    p1[r] += h2 * w31[nf];
                }
            }
#pragma unroll
            for (int mk = 1; mk < 16; mk <<= 1) {
#pragma unroll
                for (int r = 0; r < 4; ++r) {
                    p0[r] += __shfl_xor(p0[r], mk);
                    p1[r] += __shfl_xor(p1[r], mk);
                }
            }
            if (owner) {
                const int ridx_o = c_perms[pio][s];
                float pf = ((ln == 0) ? p0[0] : (ln == 1) ? p0[1] : (ln == 2) ? p0[2] : p0[3]) + b30;
                float z  = ((ln == 0) ? p1[0] : (ln == 1) ? p1[1] : (ln == 2) ? p1[2] : p1[3]) + b31;
                float gt_f = (ridx_o == 0) ? ffo[0] : (ridx_o == 1) ? ffo[1] : ffo[2];
                float gt_p = (ridx_o == 0) ? ppo[0] : (ridx_o == 1) ? ppo[1] : ppo[2];
                float m    = (ridx_o == 0) ? mmo[0] : (ridx_o == 1) ? mmo[1] : mmo[2];
                float d = pf - gt_f;
                float pl = (fmaxf(z, 0.f) - z * gt_p + __logf(1.0f + __expf(-fabsf(z)))) * m;
                lossAcc += d * d * m + pl;
                maskAcc += m;
                bool msk = m > 0.5f;
                float act_f = msk ? pf : gt_f;
                float act_p = msk ? (1.f / (1.f + __expf(-z))) : gt_p;
                stl[rloc * 2 + 0] = act_f;
                stl[rloc * 2 + 1] = act_p;
                dec_f[R_own * 3 + ridx_o] = act_f;
                dec_p[R_own * 3 + ridx_o] = act_p;
            }
            if (s < 2) {                       // same-wave LDS exchange (DS in order)
                float af_ = stl[ln * 2 + 0];
                float ap_ = stl[ln * 2 + 1];
                const float* w0r = &W1[(size_t)(DDIM + ridx_h * 3 + 0) * HDIM];
                const float* w1r = &W1[(size_t)(DDIM + ridx_h * 3 + 1) * HDIM];
                const float* w2r = &W1[(size_t)(DDIM + ridx_h * 3 + 2) * HDIM];
#pragma unroll
                for (int ks = 0; ks < 4; ++ks) {
                    const int c0 = ks * 32 + g * 8;
                    f32x4 a0 = *reinterpret_cast<const f32x4*>(w0r + c0);
                    f32x4 a1 = *reinterpret_cast<const f32x4*>(w0r + c0 + 4);
                    f32x4 b0 = *reinterpret_cast<const f32x4*>(w1r + c0);
                    f32x4 b1x = *reinterpret_cast<const f32x4*>(w1r + c0 + 4);
                    f32x4 c0v = *reinterpret_cast<const f32x4*>(w2r + c0);
                    f32x4 c1v = *reinterpret_cast<const f32x4*>(w2r + c0 + 4);
#pragma unroll
                    for (int j = 0; j < 4; ++j) {
                        scon[ks * 8 + j]     += af_ * a0[j] + ap_ * b0[j]  + c0v[j];
                        scon[ks * 8 + 4 + j] += af_ * a1[j] + ap_ * b1x[j] + c1v[j];
                    }
                }
            }
        }
    }
    // ---- wave loss reduce + block combine (single end barrier)
#pragma unroll
    for (int mk = 1; mk < 64; mk <<= 1) {
        lossAcc += __shfl_xor(lossAcc, mk);
        maskAcc += __shfl_xor(maskAcc, mk);
    }
    if (lane == 0) { lossw[0] = lossAcc; lossw[1] = maskAcc; }
    __syncthreads();
    if (t == 0) {
        float ls = 0.f, ms = 0.f;
#pragma unroll
        for (int w = 0; w < 4; ++w) {
            const float* lw = (const float*)(lds + 32768 + w * 12288 + 8448);
            ls += lw[0]; ms += lw[1];
        }
        partials[2 * (size_t)blockIdx.x]     = ls;
        partials[2 * (size_t)blockIdx.x + 1] = ms;
    }
}

// ---------------- K3: deterministic final reduction ----------------
__global__ __launch_bounds__(256) void k3_reduce(const float* __restrict__ partials,
                                                 int nb, float* __restrict__ out)
{
    __shared__ float sl[256], sm[256];
    int t = threadIdx.x;
    float ls = 0.f, ms = 0.f;
    for (int i = t; i < nb; i += 256) { ls += partials[2 * i]; ms += partials[2 * i + 1]; }
    sl[t] = ls; sm[t] = ms;
    __syncthreads();
    for (int s = 128; s > 0; s >>= 1) {
        if (t < s) { sl[t] += sl[t + s]; sm[t] += sm[t + s]; }
        __syncthreads();
    }
    if (t == 0) out[0] = sl[0] / (sm[0] + 1e-8f);
}

extern "C" void kernel_launch(void* const* d_in, const int* in_sizes, int n_in,
                              void* d_out, int out_size, void* d_ws, size_t ws_size,
                              hipStream_t stream) {
    const float* seq   = (const float*)d_in[0];
    const float* freq  = (const float*)d_in[1];
    const float* pres  = (const float*)d_in[2];
    const float* rmask = (const float*)d_in[3];
    const int*   pidx  = (const int*)d_in[4];
    const float* W1    = (const float*)d_in[5];
    const float* b1    = (const float*)d_in[6];
    const float* W2    = (const float*)d_in[7];
    const float* b2    = (const float*)d_in[8];
    const float* W3    = (const float*)d_in[9];
    const float* b3    = (const float*)d_in[10];

    int B = in_sizes[4];
    float* out   = (float*)d_out;
    float* dec_f = out + 1;
    float* dec_p = out + 1 + (size_t)B * 3;

    char* ws = (char*)d_ws;
    float*  partials = (float*)ws;                        // 16 KB reserved
    ushort* w1s  = (ushort*)(ws + 16384);                 // 256 KB
    ushort* w2t  = (ushort*)(ws + 16384 + 262144);        // 32 KB

    int nblk = B / 128;                                   // 1024
    k0_prep<<<(DDIM * HDIM + HDIM * HDIM + 255) / 256, 256, 0, stream>>>(W1, W2, w1s, w2t);
    kf_fused<<<nblk, 256, 0, stream>>>(seq, w1s, w2t, freq, pres, rmask, pidx,
                                       W1, b1, b2, W3, b3, dec_f, dec_p, partials);
    k3_reduce<<<1, 256, 0, stream>>>(partials, nblk, out);
}